// Round 1
// baseline (52.333 us; speedup 1.0000x reference)
//
#include <hip/hip_runtime.h>

// Problem constants (from reference setup_inputs)
#define B_DIM   4
#define A_DIM   200
#define F_DIM   128
#define OUT_DIM 128

// Kernel A: per-(b,a)-row dual half-GEMM.
// h layout in workspace: [0 .. 800*128)       = h_i + bias
//                        [800*128 .. 2*800*128) = h_j
__global__ void __launch_bounds__(128) gemm_h_kernel(
    const float* __restrict__ x,      // [B*A, F]
    const float* __restrict__ W,      // [2F, OUT]
    const float* __restrict__ bias,   // [OUT]
    float* __restrict__ h)            // [2, B*A, OUT]
{
    const int row = blockIdx.x;       // 0..799  (b*A + a)
    const int o   = threadIdx.x;      // 0..127
    __shared__ float xs[F_DIM];
    xs[o] = x[row * F_DIM + o];
    __syncthreads();

    float acc1 = 0.f, acc2 = 0.f;
#pragma unroll
    for (int f = 0; f < F_DIM; ++f) {
        const float xv = xs[f];                       // LDS broadcast, no conflict
        acc1 = fmaf(xv, W[f * OUT_DIM + o], acc1);            // W[:F] coalesced
        acc2 = fmaf(xv, W[(F_DIM + f) * OUT_DIM + o], acc2);  // W[F:] coalesced
    }
    h[row * OUT_DIM + o]                         = acc1 + bias[o];
    h[(B_DIM * A_DIM + row) * OUT_DIM + o]       = acc2;
}

// Kernel B: write-bound broadcast expand, float4-vectorized, grid-stride.
// out flat float index: (((b*A+i)*A + j)*3 + c)*128 + o
// in float4 units v:    r = v>>5 = ((b*A+i)*A + j)*3 + c ; o4 = v&31
// dist flat index == r exactly.
__global__ void __launch_bounds__(256) expand_kernel(
    const float4* __restrict__ h4,    // hi4 then hj4
    const float* __restrict__ dist,   // [B*A*A*3]
    float4* __restrict__ out,         // [B*A*A*3*(OUT/4)]
    unsigned total4)
{
    const float4* __restrict__ hi4 = h4;
    const float4* __restrict__ hj4 = h4 + B_DIM * A_DIM * (OUT_DIM / 4);
    const unsigned stride = gridDim.x * blockDim.x;
    for (unsigned v = blockIdx.x * blockDim.x + threadIdx.x; v < total4; v += stride) {
        const unsigned o4    = v & 31u;
        const unsigned r     = v >> 5;           // ((b*A+i)*A + j)*3 + c
        const unsigned jrow  = r / 3u;           // (b*A+i)*A + j   (magic-mul)
        const unsigned birow = jrow / 200u;      // b*A + i         (magic-mul)
        const unsigned j     = jrow - birow * 200u;
        const unsigned b     = birow / 200u;

        const float  d  = dist[r];                          // broadcast across 32 lanes
        const float4 hi = hi4[birow * 32u + o4];            // L1/L2-resident
        const float4 hj = hj4[(b * 200u + j) * 32u + o4];   // L1/L2-resident

        float4 res;
        res.x = (hi.x + hj.x) * d;
        res.y = (hi.y + hj.y) * d;
        res.z = (hi.z + hj.z) * d;
        res.w = (hi.w + hj.w) * d;
        out[v] = res;                                       // coalesced 16B/lane
    }
}

extern "C" void kernel_launch(void* const* d_in, const int* in_sizes, int n_in,
                              void* d_out, int out_size, void* d_ws, size_t ws_size,
                              hipStream_t stream) {
    const float* x    = (const float*)d_in[0];   // scalar_features [B,A,F]
    const float* dist = (const float*)d_in[1];   // distances [B,A,A,3]
    const float* W    = (const float*)d_in[2];   // weight [2F,OUT]
    const float* bias = (const float*)d_in[3];   // bias [OUT]

    float* h = (float*)d_ws;  // needs 2*800*128*4 = 819,200 B of scratch

    gemm_h_kernel<<<B_DIM * A_DIM, F_DIM, 0, stream>>>(x, W, bias, h);

    const unsigned total4 = (unsigned)(out_size / 4);  // 15,360,000 float4
    expand_kernel<<<2048, 256, 0, stream>>>((const float4*)h, dist,
                                            (float4*)d_out, total4);
}